// Round 1
// 786.738 us; speedup vs baseline: 1.1093x; 1.1093x over previous
//
#include <hip/hip_runtime.h>
#include <math.h>

// Problem constants (fixed by the reference)
#define NN   20000
#define EE   320000
#define DIN  128
#define KK   8
#define HH   64
#define NEG  0.01f
#define CAP  128   // max staged edges per node in k_agg fast path (data max ~40)

typedef __attribute__((ext_vector_type(8))) short short8;   // 8 bf16 (4 VGPRs)
typedef __attribute__((ext_vector_type(4))) float f32x4;    // MFMA acc

// ---------------------------------------------------------------------------
// bf16 helpers (RNE)
// ---------------------------------------------------------------------------
__device__ __forceinline__ unsigned short f2bf(float f) {
  unsigned u = __float_as_uint(f);
  u += 0x7FFF + ((u >> 16) & 1);
  return (unsigned short)(u >> 16);
}
__device__ __forceinline__ float bf2f_lo(unsigned u) {  // low 16 bits
  return __uint_as_float(u << 16);
}
__device__ __forceinline__ float bf2f_hi(unsigned u) {  // high 16 bits
  return __uint_as_float(u & 0xFFFF0000u);
}

__device__ __forceinline__ float wave_sum(float v) {
#pragma unroll
  for (int m = 1; m < 64; m <<= 1) v += __shfl_xor(v, m, 64);
  return v;
}

// ---------------------------------------------------------------------------
// K-prep (merged): blocks [0,256) -> Wt, [256,264) -> Vt, [264,889) -> er
//   Wt[kh*64+h][d] (bf16) = W_enc[d][kh*64+h]          (B operand for k_out)
//   Vt[n][d]       (bf16) = sum_h W_enc[d,n*64+h]*attn_l[n,h], n>=8 rows zero
//   er[n][k]       (f32)  = node_feat[n,:] . W_r[k,:]
// ---------------------------------------------------------------------------
__global__ __launch_bounds__(256) void k_pre(const float* __restrict__ W_enc,
                                             const float* __restrict__ attn_l,
                                             const float* __restrict__ node_feat,
                                             const float* __restrict__ W_r,
                                             unsigned short* __restrict__ Wt,
                                             unsigned short* __restrict__ Vt,
                                             float* __restrict__ er) {
  __shared__ __align__(16) float4 wr4[KK * 32];
  int b = blockIdx.x, tid = threadIdx.x;
  if (b < 256) {                                  // ---- Wt ----
    int gid = b * 256 + tid;
    int row = gid >> 7, d = gid & 127;            // row = kh*64+h
    Wt[gid] = f2bf(W_enc[(size_t)d * 512 + row]);
  } else if (b < 264) {                           // ---- Vt ----
    int gid = (b - 256) * 256 + tid;              // 0..2047
    int n = gid >> 7, d = gid & 127;
    float acc = 0.f;
    if (n < 8) {
#pragma unroll 8
      for (int h = 0; h < HH; ++h)
        acc += W_enc[(size_t)d * 512 + n * 64 + h] * attn_l[n * 64 + h];
    }
    Vt[gid] = f2bf(acc);
  } else {                                        // ---- er ----
    wr4[tid] = ((const float4*)W_r)[tid];
    __syncthreads();
    int gid = (b - 264) * 256 + tid;
    int n = gid >> 3, k = gid & 7;
    if (n < NN) {
      const float4* nf4 = (const float4*)node_feat + (size_t)n * 32;
      float acc = 0.f;
#pragma unroll
      for (int i = 0; i < 32; ++i) {
        float4 a = nf4[i], bb = wr4[k * 32 + i];
        acc += a.x * bb.x + a.y * bb.y + a.z * bb.z + a.w * bb.w;
      }
      er[gid] = acc;
    }
  }
}

// ---------------------------------------------------------------------------
// K2+K3 fused: streaming mean -> x (bf16), round-trip the block's 16 edges
// through LDS, wave 0 computes logits via MFMA, adds er[dst], leaky, stores
// e_log, and bumps the dst histogram. One pass over edge_feat; x is written
// but never re-read here (old k_logit re-read all 82 MB of x).
// LDS tile padded to 17 uint4/row: row stride 68 dwords == 4 (mod 32) makes
// both the b128 stores (row,slice) and the MFMA fragment reads (row,quad)
// uniform over all 8 bank-groups -> conflict-free.
// ---------------------------------------------------------------------------
__global__ __launch_bounds__(256) void k_mlog(const float* __restrict__ ef,
                                              const unsigned short* __restrict__ Vt,
                                              const float* __restrict__ er,
                                              const int* __restrict__ dst,
                                              unsigned short* __restrict__ x,
                                              float* __restrict__ e_log,
                                              int* __restrict__ counts) {
  __shared__ __align__(16) uint4 xl4[16 * 17];   // 16 edges x (16+1) uint4
  int tid = threadIdx.x;
  size_t gid = (size_t)blockIdx.x * 256 + tid;   // E*16 threads
  size_t e = gid >> 4;
  int s = gid & 15;
  const float4* p = (const float4*)(ef + e * 384) + s * 2;
  float4 a0 = p[0],  a1 = p[1];
  float4 b0 = p[32], b1 = p[33];
  float4 c0 = p[64], c1 = p[65];
  const float i3 = 1.f / 3.f;
  float m0 = (a0.x + b0.x + c0.x) * i3, m1 = (a0.y + b0.y + c0.y) * i3;
  float m2 = (a0.z + b0.z + c0.z) * i3, m3 = (a0.w + b0.w + c0.w) * i3;
  float m4 = (a1.x + b1.x + c1.x) * i3, m5 = (a1.y + b1.y + c1.y) * i3;
  float m6 = (a1.z + b1.z + c1.z) * i3, m7 = (a1.w + b1.w + c1.w) * i3;
  uint4 o;
  o.x = (unsigned)f2bf(m0) | ((unsigned)f2bf(m1) << 16);
  o.y = (unsigned)f2bf(m2) | ((unsigned)f2bf(m3) << 16);
  o.z = (unsigned)f2bf(m4) | ((unsigned)f2bf(m5) << 16);
  o.w = (unsigned)f2bf(m6) | ((unsigned)f2bf(m7) << 16);
  ((uint4*)x)[gid] = o;                          // global (consumed by k_agg)
  xl4[(tid >> 4) * 17 + (tid & 15)] = o;         // LDS copy for the logit MFMA
  __syncthreads();

  if (tid < 64) {                                // wave 0: logits for 16 edges
    int lane = tid;
    int m = lane & 15, quad = lane >> 4;
    size_t e0 = (size_t)blockIdx.x * 16;
    const short8* xr = (const short8*)((const unsigned short*)xl4 + m * 136);
    const short8* vr = (const short8*)(Vt + (size_t)m * 128);
    f32x4 acc = {0.f, 0.f, 0.f, 0.f};
#pragma unroll
    for (int kt = 0; kt < 4; ++kt) {
      short8 a = xr[kt * 4 + quad];              // A[edge m][k-dim]
      short8 bfr = vr[kt * 4 + quad];            // B from transposed Vt
      acc = __builtin_amdgcn_mfma_f32_16x16x32_bf16(a, bfr, acc, 0, 0, 0);
    }
    // C layout: col = lane&15 (k-head), row = quad*4 + r (edge)
    if (m < 8) {
#pragma unroll
      for (int r = 0; r < 4; ++r) {
        size_t ee = e0 + quad * 4 + r;
        int dv = dst[ee];
        float z = acc[r] + er[(size_t)dv * 8 + m];
        z = z > 0.f ? z : NEG * z;
        e_log[ee * 8 + m] = z;
        if (m == 0) atomicAdd(&counts[dv], 1);
      }
    }
  }
}

// ---------------------------------------------------------------------------
// Hierarchical exclusive scan (3 kernels)
// ---------------------------------------------------------------------------
__device__ __forceinline__ int block_excl_scan256(int v, int tid) {
  __shared__ int wtot[4];
  int lane = tid & 63, wid = tid >> 6;
  int incl = v;
#pragma unroll
  for (int off = 1; off < 64; off <<= 1) {
    int t = __shfl_up(incl, off, 64);
    if (lane >= off) incl += t;
  }
  if (lane == 63) wtot[wid] = incl;
  __syncthreads();
  if (tid == 0) {
    int s = 0;
#pragma unroll
    for (int i = 0; i < 4; ++i) { int t = wtot[i]; wtot[i] = s; s += t; }
  }
  __syncthreads();
  return wtot[wid] + incl - v;
}

__global__ __launch_bounds__(256) void k_scan1(const int* __restrict__ counts,
                                               int* __restrict__ lexcl,
                                               int* __restrict__ btot) {
  int b = blockIdx.x, tid = threadIdx.x;
  int i = b * 256 + tid;
  int v = (i < NN) ? counts[i] : 0;
  int ex = block_excl_scan256(v, tid);
  lexcl[i] = ex;
  if (tid == 255) btot[b] = ex + v;
}

__global__ __launch_bounds__(256) void k_scan2(int* __restrict__ btot,
                                               int* __restrict__ bbase,
                                               int* __restrict__ offs) {
  int tid = threadIdx.x;
  int v = (tid < 80) ? btot[tid] : 0;
  int ex = block_excl_scan256(v, tid);
  if (tid < 80) bbase[tid] = ex;
  if (tid == 0) offs[NN] = EE;  // grand total is exactly E
}

__global__ __launch_bounds__(256) void k_scan3(const int* __restrict__ lexcl,
                                               const int* __restrict__ bbase,
                                               int* __restrict__ offs,
                                               int* __restrict__ cursor) {
  int b = blockIdx.x, tid = threadIdx.x;
  int i = b * 256 + tid;
  if (i < NN) {
    int o = lexcl[i] + bbase[b];
    offs[i] = o;
    cursor[i] = o;
  }
}

// ---------------------------------------------------------------------------
// K5: scatter edge ids into CSR
// ---------------------------------------------------------------------------
__global__ __launch_bounds__(256) void k_fill(const int* __restrict__ dst,
                                              int* __restrict__ cursor,
                                              int* __restrict__ elist) {
  int e = blockIdx.x * 256 + threadIdx.x;
  if (e < EE) {
    int p = atomicAdd(&cursor[dst[e]], 1);
    elist[p] = e;
  }
}

// ---------------------------------------------------------------------------
// K6: per-node segmented softmax + weighted aggregation.
// Fast path (cnt <= CAP, always taken for this data): elist + e_log rows are
// staged in LDS ONCE; max/sum/scale run from LDS (old code made 3 global
// passes over e_log and 4 over elist, and computed exp twice). exp is stored
// in place and scaled by 1/sum, so pass C reads ready weights.
// ---------------------------------------------------------------------------
__global__ __launch_bounds__(256) void k_agg(const int* __restrict__ offs,
                                             const int* __restrict__ elist,
                                             const float* __restrict__ e_log,
                                             const unsigned short* __restrict__ x,
                                             unsigned short* __restrict__ y) {
  __shared__ float red[4][8];
  __shared__ float maxs[8], invs[8];
  __shared__ int eids[CAP];
  __shared__ __align__(16) float w[CAP * 8];      // logits -> exp -> weights
  __shared__ __align__(16) float xs[32 * 128];    // 16 KB fp32-unpacked tiles
  int n = blockIdx.x;
  int tid = threadIdx.x, lane = tid & 63, wid = tid >> 6;
  int start = offs[n], end = offs[n + 1];
  int cnt = end - start;
  int d = tid & 127, kg = tid >> 7;               // kg in {0,1}: k = kg*4 + i
  float acc0 = 0.f, acc1 = 0.f, acc2 = 0.f, acc3 = 0.f;

  if (cnt <= CAP) {
    // ---- stage elist + e_log rows ----
    for (int i = tid; i < cnt; i += 256) eids[i] = elist[start + i];
    __syncthreads();
    for (int j = tid; j < cnt * 2; j += 256)
      ((float4*)w)[j] = ((const float4*)e_log)[(size_t)eids[j >> 1] * 2 + (j & 1)];
    __syncthreads();

    int k = tid & 7, ib = tid >> 3;               // 32 i-slots per k
    // ---- per-k max ----
    float mm = -3.4e38f;
    for (int i = ib; i < cnt; i += 32) mm = fmaxf(mm, w[i * 8 + k]);
    mm = fmaxf(mm, __shfl_xor(mm, 8, 64));
    mm = fmaxf(mm, __shfl_xor(mm, 16, 64));
    mm = fmaxf(mm, __shfl_xor(mm, 32, 64));
    if ((lane >> 3) == 0) red[wid][lane] = mm;    // lane == k for lanes 0..7
    __syncthreads();
    if (tid < 8)
      maxs[tid] = fmaxf(fmaxf(red[0][tid], red[1][tid]), fmaxf(red[2][tid], red[3][tid]));
    __syncthreads();

    // ---- per-k sum of exp (exp stored in place) ----
    float mk = maxs[k];
    float ss = 0.f;
    for (int i = ib; i < cnt; i += 32) {
      float v = __expf(w[i * 8 + k] - mk);
      w[i * 8 + k] = v;
      ss += v;
    }
    ss += __shfl_xor(ss, 8, 64);
    ss += __shfl_xor(ss, 16, 64);
    ss += __shfl_xor(ss, 32, 64);
    if ((lane >> 3) == 0) red[wid][lane] = ss;
    __syncthreads();
    if (tid < 8) {
      float tot = red[0][tid] + red[1][tid] + red[2][tid] + red[3][tid];
      invs[tid] = tot > 0.f ? 1.f / tot : 0.f;
    }
    __syncthreads();
    float iv = invs[k];
    for (int i = ib; i < cnt; i += 32) w[i * 8 + k] *= iv;
    __syncthreads();

    // ---- weighted aggregation, 32-edge batches staged in LDS ----
    for (int base = 0; base < cnt; base += 32) {
      int nb = min(32, cnt - base);
      for (int j = tid; j < nb * 16; j += 256) {
        size_t e = (size_t)eids[base + (j >> 4)];
        uint4 t = ((const uint4*)x)[e * 16 + (j & 15)];
        float4 lo = make_float4(bf2f_lo(t.x), bf2f_hi(t.x), bf2f_lo(t.y), bf2f_hi(t.y));
        float4 hi = make_float4(bf2f_lo(t.z), bf2f_hi(t.z), bf2f_lo(t.w), bf2f_hi(t.w));
        ((float4*)xs)[(j >> 4) * 32 + (j & 15) * 2 + 0] = lo;
        ((float4*)xs)[(j >> 4) * 32 + (j & 15) * 2 + 1] = hi;
      }
      __syncthreads();
      for (int j = 0; j < nb; ++j) {
        float xv = xs[j * 128 + d];
        const float* wp = &w[(base + j) * 8 + kg * 4];
        acc0 += wp[0] * xv; acc1 += wp[1] * xv; acc2 += wp[2] * xv; acc3 += wp[3] * xv;
      }
      __syncthreads();
    }
  } else {
    // ---- fallback: original 3-pass global path (never taken for this data) ----
    float m8[8];
#pragma unroll
    for (int k = 0; k < 8; ++k) m8[k] = -3.4e38f;
    for (int i = start + tid; i < end; i += 256) {
      size_t e = (size_t)elist[i];
      float4 a = ((const float4*)e_log)[e * 2 + 0];
      float4 b = ((const float4*)e_log)[e * 2 + 1];
      m8[0] = fmaxf(m8[0], a.x); m8[1] = fmaxf(m8[1], a.y);
      m8[2] = fmaxf(m8[2], a.z); m8[3] = fmaxf(m8[3], a.w);
      m8[4] = fmaxf(m8[4], b.x); m8[5] = fmaxf(m8[5], b.y);
      m8[6] = fmaxf(m8[6], b.z); m8[7] = fmaxf(m8[7], b.w);
    }
#pragma unroll
    for (int k = 0; k < 8; ++k) {
#pragma unroll
      for (int mm2 = 1; mm2 < 64; mm2 <<= 1)
        m8[k] = fmaxf(m8[k], __shfl_xor(m8[k], mm2, 64));
    }
    if (lane == 0) {
#pragma unroll
      for (int k = 0; k < 8; ++k) red[wid][k] = m8[k];
    }
    __syncthreads();
    if (tid < 8)
      maxs[tid] = fmaxf(fmaxf(red[0][tid], red[1][tid]), fmaxf(red[2][tid], red[3][tid]));
    __syncthreads();
    float mk8[8];
#pragma unroll
    for (int k = 0; k < 8; ++k) mk8[k] = maxs[k];
    float s8[8];
#pragma unroll
    for (int k = 0; k < 8; ++k) s8[k] = 0.f;
    for (int i = start + tid; i < end; i += 256) {
      size_t e = (size_t)elist[i];
      float4 a = ((const float4*)e_log)[e * 2 + 0];
      float4 b = ((const float4*)e_log)[e * 2 + 1];
      s8[0] += __expf(a.x - mk8[0]); s8[1] += __expf(a.y - mk8[1]);
      s8[2] += __expf(a.z - mk8[2]); s8[3] += __expf(a.w - mk8[3]);
      s8[4] += __expf(b.x - mk8[4]); s8[5] += __expf(b.y - mk8[5]);
      s8[6] += __expf(b.z - mk8[6]); s8[7] += __expf(b.w - mk8[7]);
    }
#pragma unroll
    for (int k = 0; k < 8; ++k) s8[k] = wave_sum(s8[k]);
    if (lane == 0) {
#pragma unroll
      for (int k = 0; k < 8; ++k) red[wid][k] = s8[k];
    }
    __syncthreads();
    if (tid < 8) {
      float tot = red[0][tid] + red[1][tid] + red[2][tid] + red[3][tid];
      invs[tid] = tot > 0.f ? 1.f / tot : 0.f;
    }
    __syncthreads();
    for (int base = start; base < end; base += 32) {
      int nb = min(32, end - base);
      for (int j = tid; j < nb * 16; j += 256) {
        size_t e = (size_t)elist[base + (j >> 4)];
        uint4 t = ((const uint4*)x)[e * 16 + (j & 15)];
        float4 lo = make_float4(bf2f_lo(t.x), bf2f_hi(t.x), bf2f_lo(t.y), bf2f_hi(t.y));
        float4 hi = make_float4(bf2f_lo(t.z), bf2f_hi(t.z), bf2f_lo(t.w), bf2f_hi(t.w));
        ((float4*)xs)[(j >> 4) * 32 + (j & 15) * 2 + 0] = lo;
        ((float4*)xs)[(j >> 4) * 32 + (j & 15) * 2 + 1] = hi;
      }
      if (tid < nb * 8) {
        size_t e = (size_t)elist[base + (tid >> 3)];
        int kk = tid & 7;
        w[tid] = __expf(e_log[e * 8 + kk] - maxs[kk]) * invs[kk];
      }
      __syncthreads();
      for (int j = 0; j < nb; ++j) {
        float xv = xs[j * 128 + d];
        float4 wv = *(const float4*)&w[j * 8 + kg * 4];
        acc0 += wv.x * xv; acc1 += wv.y * xv; acc2 += wv.z * xv; acc3 += wv.w * xv;
      }
      __syncthreads();
    }
  }

  size_t yb = ((size_t)n * 8 + kg * 4) * 128 + d;
  y[yb + 0 * 128] = f2bf(acc0);
  y[yb + 1 * 128] = f2bf(acc1);
  y[yb + 2 * 128] = f2bf(acc2);
  y[yb + 3 * 128] = f2bf(acc3);
}

// ---------------------------------------------------------------------------
// K7: out[n, kh*64+h] = y[n,kh,:] @ Wt[kh*64+h,:]  via MFMA.
// Block: 16 nodes x 64 h for one kh; wave w owns h-tile w.
// (Kept separate from k_agg: per-node blocks cannot amortize the 128 KB Wt
//  panel that 16-node batching amortizes here.)
// ---------------------------------------------------------------------------
__global__ __launch_bounds__(256) void k_out(const unsigned short* __restrict__ y,
                                             const unsigned short* __restrict__ Wt,
                                             float* __restrict__ out) {
  int kh = blockIdx.y;
  int n0 = blockIdx.x * 16;
  int wv = threadIdx.x >> 6;
  int lane = threadIdx.x & 63;
  int m = lane & 15, quad = lane >> 4;
  int h0 = wv * 16;
  const short8* ar = (const short8*)(y + ((size_t)(n0 + m) * 8 + kh) * 128);
  const short8* br = (const short8*)(Wt + (size_t)(kh * 64 + h0 + m) * 128);
  f32x4 acc = {0.f, 0.f, 0.f, 0.f};
#pragma unroll
  for (int kt = 0; kt < 4; ++kt) {
    short8 a = ar[kt * 4 + quad];
    short8 b = br[kt * 4 + quad];
    acc = __builtin_amdgcn_mfma_f32_16x16x32_bf16(a, b, acc, 0, 0, 0);
  }
#pragma unroll
  for (int r = 0; r < 4; ++r)
    out[(size_t)(n0 + quad * 4 + r) * 512 + kh * 64 + h0 + m] = acc[r];
}

// ---------------------------------------------------------------------------
// launch
// ---------------------------------------------------------------------------
extern "C" void kernel_launch(void* const* d_in, const int* in_sizes, int n_in,
                              void* d_out, int out_size, void* d_ws, size_t ws_size,
                              hipStream_t stream) {
  const float* node_feat = (const float*)d_in[0];
  const float* edge_feat = (const float*)d_in[1];
  const float* W_enc     = (const float*)d_in[2];
  const float* attn_l    = (const float*)d_in[3];
  const float* W_r       = (const float*)d_in[4];
  const int*   dst       = (const int*)d_in[5];
  float* out = (float*)d_out;

  char* ws = (char*)d_ws;
  size_t off = 0;
  auto carve = [&](size_t bytes) {
    void* p = ws + off;
    off = (off + bytes + 255) & ~(size_t)255;
    return p;
  };
  unsigned short* x   = (unsigned short*)carve((size_t)EE * DIN * 2);     // 81.9 MB
  unsigned short* y   = (unsigned short*)carve((size_t)NN * KK * DIN * 2);// 41.0 MB
  unsigned short* Vt  = (unsigned short*)carve(16 * 128 * 2);
  unsigned short* Wt  = (unsigned short*)carve((size_t)KK * HH * DIN * 2);// 128 KB
  float* er    = (float*)carve((size_t)NN * KK * 4);
  float* e_log = (float*)carve((size_t)EE * KK * 4);                       // 10.2 MB
  int* counts  = (int*)carve((size_t)20480 * 4);
  int* lexcl   = (int*)carve((size_t)20480 * 4);
  int* btot    = (int*)carve(80 * 4);
  int* bbase   = (int*)carve(80 * 4);
  int* offs    = (int*)carve((size_t)(NN + 1) * 4);
  int* cursor  = (int*)carve((size_t)NN * 4);
  int* elist   = (int*)carve((size_t)EE * 4);
  (void)ws_size; (void)in_sizes; (void)n_in; (void)out_size;

  hipMemsetAsync(counts, 0, (size_t)NN * 4, stream);

  k_pre <<<264 + (NN * KK) / 256, 256, 0, stream>>>(W_enc, attn_l, node_feat, W_r,
                                                    Wt, Vt, er);
  k_mlog<<<(EE * 16) / 256, 256, 0, stream>>>(edge_feat, Vt, er, dst, x, e_log, counts);
  k_scan1<<<80, 256, 0, stream>>>(counts, lexcl, btot);
  k_scan2<<<1, 256, 0, stream>>>(btot, bbase, offs);
  k_scan3<<<80, 256, 0, stream>>>(lexcl, bbase, offs, cursor);
  k_fill<<<EE / 256, 256, 0, stream>>>(dst, cursor, elist);
  k_agg <<<NN, 256, 0, stream>>>(offs, elist, e_log, x, y);
  k_out <<<dim3(NN / 16, KK), 256, 0, stream>>>(y, Wt, out);
}

// Round 2
// 779.547 us; speedup vs baseline: 1.1195x; 1.0092x over previous
//
#include <hip/hip_runtime.h>
#include <math.h>

// Problem constants (fixed by the reference)
#define NN   20000
#define EE   320000
#define DIN  128
#define KK   8
#define HH   64
#define NEG  0.01f
#define CAP  128   // max staged edges per node in k_agg fast path (data max ~40)

typedef __attribute__((ext_vector_type(8))) short short8;   // 8 bf16 (4 VGPRs)
typedef __attribute__((ext_vector_type(4))) float f32x4;    // MFMA acc

// ---------------------------------------------------------------------------
// bf16 helpers (RNE)
// ---------------------------------------------------------------------------
__device__ __forceinline__ unsigned short f2bf(float f) {
  unsigned u = __float_as_uint(f);
  u += 0x7FFF + ((u >> 16) & 1);
  return (unsigned short)(u >> 16);
}
__device__ __forceinline__ float bf2f_lo(unsigned u) {  // low 16 bits
  return __uint_as_float(u << 16);
}
__device__ __forceinline__ float bf2f_hi(unsigned u) {  // high 16 bits
  return __uint_as_float(u & 0xFFFF0000u);
}

__device__ __forceinline__ float wave_sum(float v) {
#pragma unroll
  for (int m = 1; m < 64; m <<= 1) v += __shfl_xor(v, m, 64);
  return v;
}

// ---------------------------------------------------------------------------
// K-prep (merged): blocks [0,256) -> Wt, [256,264) -> Vt, [264,889) -> er,
//                  blocks [889,2139) -> dst histogram (CSR counts)
//   Wt[kh*64+h][d] (bf16) = W_enc[d][kh*64+h]          (B operand for k_out)
//   Vt[n][d]       (bf16) = sum_h W_enc[d,n*64+h]*attn_l[n,h], n>=8 rows zero
//   er[n][k]       (f32)  = node_feat[n,:] . W_r[k,:]
// ---------------------------------------------------------------------------
__global__ __launch_bounds__(256) void k_pre(const float* __restrict__ W_enc,
                                             const float* __restrict__ attn_l,
                                             const float* __restrict__ node_feat,
                                             const float* __restrict__ W_r,
                                             const int* __restrict__ dst,
                                             unsigned short* __restrict__ Wt,
                                             unsigned short* __restrict__ Vt,
                                             float* __restrict__ er,
                                             int* __restrict__ counts) {
  __shared__ __align__(16) float4 wr4[KK * 32];
  int b = blockIdx.x, tid = threadIdx.x;
  if (b < 256) {                                  // ---- Wt ----
    int gid = b * 256 + tid;
    int row = gid >> 7, d = gid & 127;            // row = kh*64+h
    Wt[gid] = f2bf(W_enc[(size_t)d * 512 + row]);
  } else if (b < 264) {                           // ---- Vt ----
    int gid = (b - 256) * 256 + tid;              // 0..2047
    int n = gid >> 7, d = gid & 127;
    float acc = 0.f;
    if (n < 8) {
#pragma unroll 8
      for (int h = 0; h < HH; ++h)
        acc += W_enc[(size_t)d * 512 + n * 64 + h] * attn_l[n * 64 + h];
    }
    Vt[gid] = f2bf(acc);
  } else if (b < 889) {                           // ---- er ----
    wr4[tid] = ((const float4*)W_r)[tid];
    __syncthreads();
    int gid = (b - 264) * 256 + tid;
    int n = gid >> 3, k = gid & 7;
    if (n < NN) {
      const float4* nf4 = (const float4*)node_feat + (size_t)n * 32;
      float acc = 0.f;
#pragma unroll
      for (int i = 0; i < 32; ++i) {
        float4 a = nf4[i], bb = wr4[k * 32 + i];
        acc += a.x * bb.x + a.y * bb.y + a.z * bb.z + a.w * bb.w;
      }
      er[gid] = acc;
    }
  } else {                                        // ---- dst histogram ----
    int i = (b - 889) * 256 + tid;                // EE == 1250*256 exactly
    atomicAdd(&counts[dst[i]], 1);
  }
}

// ---------------------------------------------------------------------------
// K2+K3 fused, CSR-direct: streaming mean -> claim CSR slot p for the edge
// (atomic cursor), scatter the x row to x[p], round-trip the block's 16 edges
// through LDS, wave 0 computes logits via MFMA, adds er[dst], leaky, stores
// e_log at row p. After this kernel, x and e_log are ALREADY in CSR order:
// k_agg reads them contiguously (no elist, no gathers, no k_fill kernel).
// LDS tile padded to 17 uint4/row -> conflict-free b128 on both sides.
// ---------------------------------------------------------------------------
__global__ __launch_bounds__(256) void k_mlog(const float* __restrict__ ef,
                                              const unsigned short* __restrict__ Vt,
                                              const float* __restrict__ er,
                                              const int* __restrict__ dst,
                                              int* __restrict__ cursor,
                                              unsigned short* __restrict__ x,
                                              float* __restrict__ e_log) {
  __shared__ __align__(16) uint4 xl4[16 * 17];   // 16 edges x (16+1) uint4
  __shared__ int pl[16], dl[16];
  int tid = threadIdx.x;
  size_t gid = (size_t)blockIdx.x * 256 + tid;   // E*16 threads
  size_t e = gid >> 4;
  int s = gid & 15;
  const float4* p4 = (const float4*)(ef + e * 384) + s * 2;
  float4 a0 = p4[0],  a1 = p4[1];
  float4 b0 = p4[32], b1 = p4[33];
  float4 c0 = p4[64], c1 = p4[65];
  const float i3 = 1.f / 3.f;
  float m0 = (a0.x + b0.x + c0.x) * i3, m1 = (a0.y + b0.y + c0.y) * i3;
  float m2 = (a0.z + b0.z + c0.z) * i3, m3 = (a0.w + b0.w + c0.w) * i3;
  float m4 = (a1.x + b1.x + c1.x) * i3, m5 = (a1.y + b1.y + c1.y) * i3;
  float m6 = (a1.z + b1.z + c1.z) * i3, m7 = (a1.w + b1.w + c1.w) * i3;
  uint4 o;
  o.x = (unsigned)f2bf(m0) | ((unsigned)f2bf(m1) << 16);
  o.y = (unsigned)f2bf(m2) | ((unsigned)f2bf(m3) << 16);
  o.z = (unsigned)f2bf(m4) | ((unsigned)f2bf(m5) << 16);
  o.w = (unsigned)f2bf(m6) | ((unsigned)f2bf(m7) << 16);
  xl4[(tid >> 4) * 17 + s] = o;                  // LDS copy for the logit MFMA

  if (tid < 16) {                                // claim CSR slots
    int ee = blockIdx.x * 16 + tid;
    int dv = dst[ee];
    pl[tid] = atomicAdd(&cursor[dv], 1);
    dl[tid] = dv;
  }
  __syncthreads();

  // scatter this thread's x-row slice to its CSR slot (row = 256 B)
  ((uint4*)x)[(size_t)pl[tid >> 4] * 16 + s] = o;

  if (tid < 64) {                                // wave 0: logits for 16 edges
    int lane = tid;
    int m = lane & 15, quad = lane >> 4;
    const short8* xr = (const short8*)((const unsigned short*)xl4 + m * 136);
    const short8* vr = (const short8*)(Vt + (size_t)m * 128);
    f32x4 acc = {0.f, 0.f, 0.f, 0.f};
#pragma unroll
    for (int kt = 0; kt < 4; ++kt) {
      short8 a = xr[kt * 4 + quad];              // A[edge m][k-dim]
      short8 bfr = vr[kt * 4 + quad];            // B from transposed Vt
      acc = __builtin_amdgcn_mfma_f32_16x16x32_bf16(a, bfr, acc, 0, 0, 0);
    }
    // C layout: col = lane&15 (k-head), row = quad*4 + r (edge)
    if (m < 8) {
#pragma unroll
      for (int r = 0; r < 4; ++r) {
        int le = quad * 4 + r;
        int dv = dl[le];
        float z = acc[r] + er[(size_t)dv * 8 + m];
        z = z > 0.f ? z : NEG * z;
        e_log[(size_t)pl[le] * 8 + m] = z;       // CSR-ordered logit row
      }
    }
  }
}

// ---------------------------------------------------------------------------
// Hierarchical exclusive scan (3 kernels)
// ---------------------------------------------------------------------------
__device__ __forceinline__ int block_excl_scan256(int v, int tid) {
  __shared__ int wtot[4];
  int lane = tid & 63, wid = tid >> 6;
  int incl = v;
#pragma unroll
  for (int off = 1; off < 64; off <<= 1) {
    int t = __shfl_up(incl, off, 64);
    if (lane >= off) incl += t;
  }
  if (lane == 63) wtot[wid] = incl;
  __syncthreads();
  if (tid == 0) {
    int s = 0;
#pragma unroll
    for (int i = 0; i < 4; ++i) { int t = wtot[i]; wtot[i] = s; s += t; }
  }
  __syncthreads();
  return wtot[wid] + incl - v;
}

__global__ __launch_bounds__(256) void k_scan1(const int* __restrict__ counts,
                                               int* __restrict__ lexcl,
                                               int* __restrict__ btot) {
  int b = blockIdx.x, tid = threadIdx.x;
  int i = b * 256 + tid;
  int v = (i < NN) ? counts[i] : 0;
  int ex = block_excl_scan256(v, tid);
  lexcl[i] = ex;
  if (tid == 255) btot[b] = ex + v;
}

__global__ __launch_bounds__(256) void k_scan2(int* __restrict__ btot,
                                               int* __restrict__ bbase,
                                               int* __restrict__ offs) {
  int tid = threadIdx.x;
  int v = (tid < 80) ? btot[tid] : 0;
  int ex = block_excl_scan256(v, tid);
  if (tid < 80) bbase[tid] = ex;
  if (tid == 0) offs[NN] = EE;  // grand total is exactly E
}

__global__ __launch_bounds__(256) void k_scan3(const int* __restrict__ lexcl,
                                               const int* __restrict__ bbase,
                                               int* __restrict__ offs,
                                               int* __restrict__ cursor) {
  int b = blockIdx.x, tid = threadIdx.x;
  int i = b * 256 + tid;
  if (i < NN) {
    int o = lexcl[i] + bbase[b];
    offs[i] = o;
    cursor[i] = o;
  }
}

// ---------------------------------------------------------------------------
// K6: per-node segmented softmax + weighted aggregation, CSR-contiguous.
// e_log rows [start,end) staged once with coalesced float4 loads; max/sum/
// scale run from LDS; x rows stream in contiguously (dwordx4, no indices).
// ---------------------------------------------------------------------------
__global__ __launch_bounds__(256) void k_agg(const int* __restrict__ offs,
                                             const float* __restrict__ e_log,
                                             const unsigned short* __restrict__ x,
                                             unsigned short* __restrict__ y) {
  __shared__ float red[4][8];
  __shared__ float maxs[8], invs[8];
  __shared__ __align__(16) float w[CAP * 8];      // logits -> exp -> weights
  __shared__ __align__(16) float xs[32 * 128];    // 16 KB fp32-unpacked tiles
  int n = blockIdx.x;
  int tid = threadIdx.x, lane = tid & 63, wid = tid >> 6;
  int start = offs[n], end = offs[n + 1];
  int cnt = end - start;
  int d = tid & 127, kg = tid >> 7;               // kg in {0,1}: k = kg*4 + i
  float acc0 = 0.f, acc1 = 0.f, acc2 = 0.f, acc3 = 0.f;

  if (cnt <= CAP) {
    // ---- stage e_log rows: one contiguous block ----
    for (int j = tid; j < cnt * 2; j += 256)
      ((float4*)w)[j] = ((const float4*)e_log)[(size_t)start * 2 + j];
    __syncthreads();

    int k = tid & 7, ib = tid >> 3;               // 32 i-slots per k
    // ---- per-k max ----
    float mm = -3.4e38f;
    for (int i = ib; i < cnt; i += 32) mm = fmaxf(mm, w[i * 8 + k]);
    mm = fmaxf(mm, __shfl_xor(mm, 8, 64));
    mm = fmaxf(mm, __shfl_xor(mm, 16, 64));
    mm = fmaxf(mm, __shfl_xor(mm, 32, 64));
    if ((lane >> 3) == 0) red[wid][lane] = mm;    // lane == k for lanes 0..7
    __syncthreads();
    if (tid < 8)
      maxs[tid] = fmaxf(fmaxf(red[0][tid], red[1][tid]), fmaxf(red[2][tid], red[3][tid]));
    __syncthreads();

    // ---- per-k sum of exp (exp stored in place) ----
    float mk = maxs[k];
    float ss = 0.f;
    for (int i = ib; i < cnt; i += 32) {
      float v = __expf(w[i * 8 + k] - mk);
      w[i * 8 + k] = v;
      ss += v;
    }
    ss += __shfl_xor(ss, 8, 64);
    ss += __shfl_xor(ss, 16, 64);
    ss += __shfl_xor(ss, 32, 64);
    if ((lane >> 3) == 0) red[wid][lane] = ss;
    __syncthreads();
    if (tid < 8) {
      float tot = red[0][tid] + red[1][tid] + red[2][tid] + red[3][tid];
      invs[tid] = tot > 0.f ? 1.f / tot : 0.f;
    }
    __syncthreads();
    float iv = invs[k];
    for (int i = ib; i < cnt; i += 32) w[i * 8 + k] *= iv;
    __syncthreads();

    // ---- weighted aggregation, 32-edge batches, contiguous x stream ----
    for (int base = 0; base < cnt; base += 32) {
      int nb = min(32, cnt - base);
      for (int j = tid; j < nb * 16; j += 256) {
        uint4 t = ((const uint4*)x)[((size_t)start + base) * 16 + j];
        float4 lo = make_float4(bf2f_lo(t.x), bf2f_hi(t.x), bf2f_lo(t.y), bf2f_hi(t.y));
        float4 hi = make_float4(bf2f_lo(t.z), bf2f_hi(t.z), bf2f_lo(t.w), bf2f_hi(t.w));
        ((float4*)xs)[(j >> 4) * 32 + (j & 15) * 2 + 0] = lo;
        ((float4*)xs)[(j >> 4) * 32 + (j & 15) * 2 + 1] = hi;
      }
      __syncthreads();
      for (int j = 0; j < nb; ++j) {
        float xv = xs[j * 128 + d];
        const float* wp = &w[(base + j) * 8 + kg * 4];
        acc0 += wp[0] * xv; acc1 += wp[1] * xv; acc2 += wp[2] * xv; acc3 += wp[3] * xv;
      }
      __syncthreads();
    }
  } else {
    // ---- fallback: multi-pass global path (never taken for this data) ----
    float m8[8];
#pragma unroll
    for (int k = 0; k < 8; ++k) m8[k] = -3.4e38f;
    for (int i = tid; i < cnt; i += 256) {
      float4 a = ((const float4*)e_log)[((size_t)start + i) * 2 + 0];
      float4 b = ((const float4*)e_log)[((size_t)start + i) * 2 + 1];
      m8[0] = fmaxf(m8[0], a.x); m8[1] = fmaxf(m8[1], a.y);
      m8[2] = fmaxf(m8[2], a.z); m8[3] = fmaxf(m8[3], a.w);
      m8[4] = fmaxf(m8[4], b.x); m8[5] = fmaxf(m8[5], b.y);
      m8[6] = fmaxf(m8[6], b.z); m8[7] = fmaxf(m8[7], b.w);
    }
#pragma unroll
    for (int k = 0; k < 8; ++k) {
#pragma unroll
      for (int mm2 = 1; mm2 < 64; mm2 <<= 1)
        m8[k] = fmaxf(m8[k], __shfl_xor(m8[k], mm2, 64));
    }
    if (lane == 0) {
#pragma unroll
      for (int k = 0; k < 8; ++k) red[wid][k] = m8[k];
    }
    __syncthreads();
    if (tid < 8)
      maxs[tid] = fmaxf(fmaxf(red[0][tid], red[1][tid]), fmaxf(red[2][tid], red[3][tid]));
    __syncthreads();
    float mk8[8];
#pragma unroll
    for (int k = 0; k < 8; ++k) mk8[k] = maxs[k];
    float s8[8];
#pragma unroll
    for (int k = 0; k < 8; ++k) s8[k] = 0.f;
    for (int i = tid; i < cnt; i += 256) {
      float4 a = ((const float4*)e_log)[((size_t)start + i) * 2 + 0];
      float4 b = ((const float4*)e_log)[((size_t)start + i) * 2 + 1];
      s8[0] += __expf(a.x - mk8[0]); s8[1] += __expf(a.y - mk8[1]);
      s8[2] += __expf(a.z - mk8[2]); s8[3] += __expf(a.w - mk8[3]);
      s8[4] += __expf(b.x - mk8[4]); s8[5] += __expf(b.y - mk8[5]);
      s8[6] += __expf(b.z - mk8[6]); s8[7] += __expf(b.w - mk8[7]);
    }
#pragma unroll
    for (int k = 0; k < 8; ++k) s8[k] = wave_sum(s8[k]);
    if (lane == 0) {
#pragma unroll
      for (int k = 0; k < 8; ++k) red[wid][k] = s8[k];
    }
    __syncthreads();
    if (tid < 8) {
      float tot = red[0][tid] + red[1][tid] + red[2][tid] + red[3][tid];
      invs[tid] = tot > 0.f ? 1.f / tot : 0.f;
    }
    __syncthreads();
    for (int base = 0; base < cnt; base += 32) {
      int nb = min(32, cnt - base);
      for (int j = tid; j < nb * 16; j += 256) {
        uint4 t = ((const uint4*)x)[((size_t)start + base) * 16 + j];
        float4 lo = make_float4(bf2f_lo(t.x), bf2f_hi(t.x), bf2f_lo(t.y), bf2f_hi(t.y));
        float4 hi = make_float4(bf2f_lo(t.z), bf2f_hi(t.z), bf2f_lo(t.w), bf2f_hi(t.w));
        ((float4*)xs)[(j >> 4) * 32 + (j & 15) * 2 + 0] = lo;
        ((float4*)xs)[(j >> 4) * 32 + (j & 15) * 2 + 1] = hi;
      }
      if (tid < nb * 8) {
        int kk = tid & 7;
        w[tid] = __expf(e_log[((size_t)start + base + (tid >> 3)) * 8 + kk] - maxs[kk]) * invs[kk];
      }
      __syncthreads();
      for (int j = 0; j < nb; ++j) {
        float xv = xs[j * 128 + d];
        float4 wv = *(const float4*)&w[j * 8 + kg * 4];
        acc0 += wv.x * xv; acc1 += wv.y * xv; acc2 += wv.z * xv; acc3 += wv.w * xv;
      }
      __syncthreads();
    }
  }

  size_t yb = ((size_t)n * 8 + kg * 4) * 128 + d;
  y[yb + 0 * 128] = f2bf(acc0);
  y[yb + 1 * 128] = f2bf(acc1);
  y[yb + 2 * 128] = f2bf(acc2);
  y[yb + 3 * 128] = f2bf(acc3);
}

// ---------------------------------------------------------------------------
// K7: out[n, kh*64+h] = y[n,kh,:] @ Wt[kh*64+h,:]  via MFMA.
// Block: 16 nodes x 64 h for one kh; wave w owns h-tile w.
// (Kept separate from k_agg: per-node blocks cannot amortize the 128 KB Wt
//  panel that 16-node batching amortizes here.)
// ---------------------------------------------------------------------------
__global__ __launch_bounds__(256) void k_out(const unsigned short* __restrict__ y,
                                             const unsigned short* __restrict__ Wt,
                                             float* __restrict__ out) {
  int kh = blockIdx.y;
  int n0 = blockIdx.x * 16;
  int wv = threadIdx.x >> 6;
  int lane = threadIdx.x & 63;
  int m = lane & 15, quad = lane >> 4;
  int h0 = wv * 16;
  const short8* ar = (const short8*)(y + ((size_t)(n0 + m) * 8 + kh) * 128);
  const short8* br = (const short8*)(Wt + (size_t)(kh * 64 + h0 + m) * 128);
  f32x4 acc = {0.f, 0.f, 0.f, 0.f};
#pragma unroll
  for (int kt = 0; kt < 4; ++kt) {
    short8 a = ar[kt * 4 + quad];
    short8 b = br[kt * 4 + quad];
    acc = __builtin_amdgcn_mfma_f32_16x16x32_bf16(a, b, acc, 0, 0, 0);
  }
#pragma unroll
  for (int r = 0; r < 4; ++r)
    out[(size_t)(n0 + quad * 4 + r) * 512 + kh * 64 + h0 + m] = acc[r];
}

// ---------------------------------------------------------------------------
// launch
// ---------------------------------------------------------------------------
extern "C" void kernel_launch(void* const* d_in, const int* in_sizes, int n_in,
                              void* d_out, int out_size, void* d_ws, size_t ws_size,
                              hipStream_t stream) {
  const float* node_feat = (const float*)d_in[0];
  const float* edge_feat = (const float*)d_in[1];
  const float* W_enc     = (const float*)d_in[2];
  const float* attn_l    = (const float*)d_in[3];
  const float* W_r       = (const float*)d_in[4];
  const int*   dst       = (const int*)d_in[5];
  float* out = (float*)d_out;

  char* ws = (char*)d_ws;
  size_t off = 0;
  auto carve = [&](size_t bytes) {
    void* p = ws + off;
    off = (off + bytes + 255) & ~(size_t)255;
    return p;
  };
  unsigned short* x   = (unsigned short*)carve((size_t)EE * DIN * 2);     // 81.9 MB
  unsigned short* y   = (unsigned short*)carve((size_t)NN * KK * DIN * 2);// 41.0 MB
  unsigned short* Vt  = (unsigned short*)carve(16 * 128 * 2);
  unsigned short* Wt  = (unsigned short*)carve((size_t)KK * HH * DIN * 2);// 128 KB
  float* er    = (float*)carve((size_t)NN * KK * 4);
  float* e_log = (float*)carve((size_t)EE * KK * 4);                       // 10.2 MB
  int* counts  = (int*)carve((size_t)20480 * 4);
  int* lexcl   = (int*)carve((size_t)20480 * 4);
  int* btot    = (int*)carve(80 * 4);
  int* bbase   = (int*)carve(80 * 4);
  int* offs    = (int*)carve((size_t)(NN + 1) * 4);
  int* cursor  = (int*)carve((size_t)NN * 4);
  (void)ws_size; (void)in_sizes; (void)n_in; (void)out_size;

  hipMemsetAsync(counts, 0, (size_t)NN * 4, stream);

  k_pre <<<889 + EE / 256, 256, 0, stream>>>(W_enc, attn_l, node_feat, W_r, dst,
                                             Wt, Vt, er, counts);
  k_scan1<<<80, 256, 0, stream>>>(counts, lexcl, btot);
  k_scan2<<<1, 256, 0, stream>>>(btot, bbase, offs);
  k_scan3<<<80, 256, 0, stream>>>(lexcl, bbase, offs, cursor);
  k_mlog<<<(EE * 16) / 256, 256, 0, stream>>>(edge_feat, Vt, er, dst, cursor, x, e_log);
  k_agg <<<NN, 256, 0, stream>>>(offs, e_log, x, y);
  k_out <<<dim3(NN / 16, KK), 256, 0, stream>>>(y, Wt, out);
}